// Round 12
// baseline (95.283 us; speedup 1.0000x reference)
//
#include <hip/hip_runtime.h>

// Sizes fixed by the problem.
#define B   32
#define S   128
#define IN  64
#define ROWS (B*S)      // 4096
#define K1  (S*IN)      // 8192
#define KCH 256         // P-GEMM k-chunks (32 k each)

__device__ __forceinline__ int rfl(int x) { return __builtin_amdgcn_readfirstlane(x); }

// ---------------------------------------------------------------------------
// Kernel 1: "prep" — 1024 blocks (4/CU, 16 waves/CU). 4 rows/block, 1 row/wave.
//   LDS-free. 'bsi,oi->bso': o indexes ROWS of W0/Ws -> lane's weights are
//   row `lane` (per-lane contiguous float4). h rows wave-uniform -> s_load.
//   Plus U1T: 4 outputs/block, one per wave (64-lane shfl reduce over t).
// ---------------------------------------------------------------------------
__global__ __launch_bounds__(256, 4) void prep_kernel(
    const float* __restrict__ h,  const float* __restrict__ W0,
    const float* __restrict__ b0, const float* __restrict__ Ws,
    const float* __restrict__ bs, const float* __restrict__ W1,
    float* __restrict__ U1T, float* __restrict__ Ab,
    float* __restrict__ Df,  float* __restrict__ C)
{
    const int bid  = blockIdx.x;
    const int tid  = threadIdx.x;
    const int lane = tid & 63;                 // = o
    const int w    = rfl(tid >> 6);            // wave id, uniform

    const int row = bid * 4 + w;               // this wave's row (uniform)
    const float4* w0row = (const float4*)(W0 + (size_t)lane * 128);
    const float4* wsrow = (const float4*)(Ws + (size_t)lane * 64);

    float a = 0.f, c = 0.f, sf = 0.f;
    #pragma unroll
    for (int ic = 0; ic < 4; ++ic) {           // i-chunks of 16 (VGPR control)
        const int i0 = ic * 16;
        float wa[16], wb[16], wsv[16];
        #pragma unroll
        for (int q = 0; q < 4; ++q) {          // per-lane contiguous 16B loads
            const float4 va = w0row[ic * 4 + q];
            const float4 vb = w0row[16 + ic * 4 + q];
            const float4 vs = wsrow[ic * 4 + q];
            wa [q*4] = va.x; wa [q*4+1] = va.y; wa [q*4+2] = va.z; wa [q*4+3] = va.w;
            wb [q*4] = vb.x; wb [q*4+1] = vb.y; wb [q*4+2] = vb.z; wb [q*4+3] = vb.w;
            wsv[q*4] = vs.x; wsv[q*4+1] = vs.y; wsv[q*4+2] = vs.z; wsv[q*4+3] = vs.w;
        }
        const float* hp = h + (size_t)row * 64 + i0;   // uniform -> s_load
        #pragma unroll
        for (int j = 0; j < 16; ++j) {
            const float hv = hp[j];
            a  += hv * wa [j];
            c  += hv * wb [j];
            sf += hv * wsv[j];
        }
    }
    const float ab = a + b0[lane];
    Ab[row * 64 + lane] = ab;                  // coalesced stores
    C [row * 64 + lane] = c;
    Df[row * 64 + lane] = sf + bs[lane] - ab - c;

    // U1T[o][o2] = sum_t W1[o2, t*64+o]; one output per wave, lane = t.
    const int g  = bid * 4 + w;                // 0..4095
    const int o2 = g >> 6, o = g & 63;
    float acc = W1[(size_t)o2 * K1 + lane * 64 + o]
              + W1[(size_t)o2 * K1 + (lane + 64) * 64 + o];
    #pragma unroll
    for (int m = 32; m; m >>= 1) acc += __shfl_xor(acc, m);
    if (lane == 0) U1T[o * 64 + o2] = acc;
}

// ---------------------------------------------------------------------------
// Kernel 2: "mid" — 1024 blocks (4/CU). P[b][o2][kc] partial GEMM.
//   block = (kc 0..255) x (b-quarter 0..3); 32 k per chunk; acc[2]/thread.
// ---------------------------------------------------------------------------
__global__ __launch_bounds__(256, 4) void mid_kernel(
    const float* __restrict__ C, const float* __restrict__ W1,
    float* __restrict__ P)
{
    const int bid  = blockIdx.x;
    const int tid  = threadIdx.x;
    const int lane = tid & 63;                 // = o2
    const int w    = rfl(tid >> 6);            // uniform

    const int kc = bid >> 2, q = bid & 3;      // kc: 0..255, q: b-quarter
    const int k0 = kc * 32;
    const float4* wrow = (const float4*)(W1 + (size_t)lane * K1 + k0);

    float acc[2] = {0, 0};                     // b = q*8 + w + 4*pp
    #pragma unroll
    for (int kq = 0; kq < 8; ++kq) {
        const float4 w4 = wrow[kq];            // per-lane contiguous, L2-resident
        #pragma unroll
        for (int pp = 0; pp < 2; ++pp) {
            const int b = q * 8 + w + 4 * pp;
            const float* cb = C + (size_t)b * K1 + k0 + kq * 4;  // uniform -> s_load
            acc[pp] += cb[0] * w4.x + cb[1] * w4.y + cb[2] * w4.z + cb[3] * w4.w;
        }
    }
    #pragma unroll
    for (int pp = 0; pp < 2; ++pp) {
        const int b = q * 8 + w + 4 * pp;
        P[((size_t)(b * 64 + lane)) * KCH + kc] = acc[pp];
    }
}

// ---------------------------------------------------------------------------
// Kernel 3: "finalk" — 1024 blocks (4/CU). block = (s 0..127) x (b-eighth),
//   one b per wave.
//   out[b,s,o2] = sum_kc P[b][o2][kc] + b1[o2]
//               + sum_o Ab[b,s,o]*U1T[o][o2] + Df[b,s,o]*W1[o2, s*64+o]
// ---------------------------------------------------------------------------
__global__ __launch_bounds__(256, 4) void final_kernel(
    const float* __restrict__ W1, const float* __restrict__ b1,
    const float* __restrict__ U1T, const float* __restrict__ Ab,
    const float* __restrict__ Df,  const float* __restrict__ P,
    float* __restrict__ out)
{
    const int bid  = blockIdx.x;
    const int tid  = threadIdx.x;
    const int lane = tid & 63;                 // = o2
    const int w    = rfl(tid >> 6);            // uniform

    const int s = bid >> 3, q = bid & 7;
    const int b = q * 4 + w;                   // this wave's b (uniform)

    // D-fold: per-lane contiguous b128 over KCH chunks
    const float4* pf = (const float4*)(P + ((size_t)(b * 64 + lane)) * KCH);
    float s0 = 0, s1 = 0, s2 = 0, s3 = 0;
    #pragma unroll
    for (int u = 0; u < KCH / 4; ++u) {
        const float4 v = pf[u];
        s0 += v.x; s1 += v.y; s2 += v.z; s3 += v.w;
    }
    float acc = b1[lane] + ((s0 + s1) + (s2 + s3));

    #pragma unroll
    for (int hh = 0; hh < 2; ++hh) {           // two 32-wide o-halves
        const int o0 = hh * 32;
        float u[32], wc[32];
        #pragma unroll
        for (int j = 0; j < 32; ++j)
            u[j] = U1T[(o0 + j) * 64 + lane];  // coalesced across lanes
        const float4* wrow = (const float4*)(W1 + (size_t)lane * K1 + s * 64 + o0);
        #pragma unroll
        for (int qq = 0; qq < 8; ++qq) {       // per-lane contiguous 128B
            const float4 v = wrow[qq];
            wc[qq*4] = v.x; wc[qq*4+1] = v.y; wc[qq*4+2] = v.z; wc[qq*4+3] = v.w;
        }
        const float* ap = Ab + ((size_t)(b * S + s)) * 64 + o0;  // uniform -> s_load
        const float* dp = Df + ((size_t)(b * S + s)) * 64 + o0;
        float t0 = 0.f;
        #pragma unroll
        for (int j = 0; j < 32; ++j)
            t0 += ap[j] * u[j] + dp[j] * wc[j];
        acc += t0;
    }

    out[((size_t)(b * S + s)) * 64 + lane] = acc;  // coalesced
}

// ---------------------------------------------------------------------------
extern "C" void kernel_launch(void* const* d_in, const int* in_sizes, int n_in,
                              void* d_out, int out_size, void* d_ws, size_t ws_size,
                              hipStream_t stream)
{
    const float* h  = (const float*)d_in[0];
    const float* W0 = (const float*)d_in[1];
    const float* b0 = (const float*)d_in[2];
    const float* Ws = (const float*)d_in[3];
    const float* bs = (const float*)d_in[4];
    const float* W1 = (const float*)d_in[5];
    const float* b1 = (const float*)d_in[6];
    float* out = (float*)d_out;

    float* ws  = (float*)d_ws;
    float* U1T = ws;                       // 4096
    float* Ab  = U1T + 64 * 64;            // 262144
    float* Df  = Ab  + ROWS * 64;          // 262144
    float* C   = Df  + ROWS * 64;          // 262144
    float* P   = C   + ROWS * 64;          // 2048*256 = 524288
    // total: ~5.1 MB of d_ws; every element read is written first each call.

    prep_kernel <<<1024, 256, 0, stream>>>(h, W0, b0, Ws, bs, W1, U1T, Ab, Df, C);
    mid_kernel  <<<1024, 256, 0, stream>>>(C, W1, P);
    final_kernel<<<1024, 256, 0, stream>>>(W1, b1, U1T, Ab, Df, P, out);
}

// Round 13
// 37.315 us; speedup vs baseline: 2.5535x; 2.5535x over previous
//
#include <hip/hip_runtime.h>

// Sizes fixed by the problem.
#define B   32
#define S   128
#define IN  64
#define ROWS (B*S)      // 4096
#define K1  (S*IN)      // 8192

__device__ __forceinline__ int rfl(int x) { return __builtin_amdgcn_readfirstlane(x); }

// ---------------------------------------------------------------------------
// Kernel 1: "prep" — 512 blocks (2/CU). 8 rows/block, 2 rows/wave (amortizes
//   the 48 weight-load instrs per wave over 2 rows). LDS-free.
//   'bsi,oi->bso': o indexes ROWS of W0/Ws -> lane o reads weight row `lane`.
//   h rows wave-uniform -> scalar pipe. Plus U1T: 8 outputs/block via
//   32-lane-group reduce.
// ---------------------------------------------------------------------------
__global__ __launch_bounds__(256, 2) void prep_kernel(
    const float* __restrict__ h,  const float* __restrict__ W0,
    const float* __restrict__ b0, const float* __restrict__ Ws,
    const float* __restrict__ bs, const float* __restrict__ W1,
    float* __restrict__ U1T, float* __restrict__ Ab,
    float* __restrict__ Df,  float* __restrict__ C)
{
    const int bid  = blockIdx.x;
    const int tid  = threadIdx.x;
    const int lane = tid & 63;                 // = o
    const int w    = rfl(tid >> 6);            // wave id, uniform

    const int row0 = bid * 8 + w * 2;          // this wave's 2 rows (uniform)
    const float4* w0row = (const float4*)(W0 + (size_t)lane * 128);
    const float4* wsrow = (const float4*)(Ws + (size_t)lane * 64);

    float a[2] = {0,0}, c[2] = {0,0}, sf[2] = {0,0};
    #pragma unroll
    for (int ic = 0; ic < 4; ++ic) {           // i-chunks of 16 (VGPR control)
        const int i0 = ic * 16;
        float wa[16], wb[16], wsv[16];
        #pragma unroll
        for (int q = 0; q < 4; ++q) {          // per-lane contiguous 16B loads
            const float4 va = w0row[ic * 4 + q];
            const float4 vb = w0row[16 + ic * 4 + q];
            const float4 vs = wsrow[ic * 4 + q];
            wa [q*4] = va.x; wa [q*4+1] = va.y; wa [q*4+2] = va.z; wa [q*4+3] = va.w;
            wb [q*4] = vb.x; wb [q*4+1] = vb.y; wb [q*4+2] = vb.z; wb [q*4+3] = vb.w;
            wsv[q*4] = vs.x; wsv[q*4+1] = vs.y; wsv[q*4+2] = vs.z; wsv[q*4+3] = vs.w;
        }
        #pragma unroll
        for (int r = 0; r < 2; ++r) {
            const float* hp = h + (size_t)(row0 + r) * 64 + i0;  // uniform -> s_load
            #pragma unroll
            for (int j = 0; j < 16; ++j) {
                const float hv = hp[j];
                a [r] += hv * wa [j];
                c [r] += hv * wb [j];
                sf[r] += hv * wsv[j];
            }
        }
    }
    const float b0v = b0[lane], bsv = bs[lane];
    #pragma unroll
    for (int r = 0; r < 2; ++r) {
        const int row = row0 + r;
        const float ab = a[r] + b0v;
        Ab[row * 64 + lane] = ab;              // coalesced stores
        C [row * 64 + lane] = c[r];
        Df[row * 64 + lane] = sf[r] + bsv - ab - c[r];
    }

    // U1T[o][o2] = sum_t W1[o2, t*64+o]; 8 outputs/block, 32 lanes each.
    const int g   = bid * 8 + (tid >> 5);      // 0..4095
    const int o2  = g >> 6, o = g & 63;
    const int sub = tid & 31;
    float acc = 0.f;
    #pragma unroll
    for (int u = 0; u < 4; ++u)
        acc += W1[(size_t)o2 * K1 + (sub + 32 * u) * 64 + o];
    #pragma unroll
    for (int m = 16; m; m >>= 1) acc += __shfl_xor(acc, m);  // within 32-group
    if (sub == 0) U1T[o * 64 + o2] = acc;
}

// ---------------------------------------------------------------------------
// Kernel 2: "dmid" — D[b][o2] = sum_k C[b,k] * W1[o2,k], computed DIRECTLY.
//   One wave per (b,o2) pair: 2048 waves = 512 blocks x 4 waves.
//   lane = k-substripe: at iter j, lane l reads the float4 at k = j*256+l*4
//   -> lanes' 16B are consecutive = perfectly coalesced 1KB/instruction,
//   for BOTH W1 and C. 64 loads + 128 FMA + 6-step shfl reduce per wave.
//   No partials buffer, no fold, no scatter.
// ---------------------------------------------------------------------------
__global__ __launch_bounds__(256, 2) void dmid_kernel(
    const float* __restrict__ C, const float* __restrict__ W1,
    float* __restrict__ D)
{
    const int bid  = blockIdx.x;
    const int tid  = threadIdx.x;
    const int lane = tid & 63;
    const int w    = rfl(tid >> 6);            // uniform

    const int g  = bid * 4 + w;                // 0..2047
    const int b  = g >> 6, o2 = g & 63;        // uniform per wave

    const float4* wrow = (const float4*)(W1 + (size_t)o2 * K1) + lane;
    const float4* crow = (const float4*)(C  + (size_t)b  * K1) + lane;

    float s0 = 0, s1 = 0, s2 = 0, s3 = 0;
    #pragma unroll
    for (int j = 0; j < 32; ++j) {             // k = j*256 + lane*4 + 0..3
        const float4 w4 = wrow[j * 64];        // coalesced 1KB across lanes
        const float4 c4 = crow[j * 64];        // coalesced 1KB across lanes
        s0 += c4.x * w4.x; s1 += c4.y * w4.y;
        s2 += c4.z * w4.z; s3 += c4.w * w4.w;
    }
    float acc = (s0 + s1) + (s2 + s3);
    #pragma unroll
    for (int m = 32; m; m >>= 1) acc += __shfl_xor(acc, m);
    if (lane == 0) D[g] = acc;
}

// ---------------------------------------------------------------------------
// Kernel 3: "finalk" — 1024 blocks (4/CU). block = (s 0..127) x (q 0..7),
//   one b = q*4+w per wave.
//   out[b,s,o2] = D[b,o2] + b1[o2]
//               + sum_o Ab[b,s,o]*U1T[o][o2] + Df[b,s,o]*W1[o2, s*64+o]
//   (P-fold replaced by ONE coalesced D load.)
// ---------------------------------------------------------------------------
__global__ __launch_bounds__(256, 4) void final_kernel(
    const float* __restrict__ W1, const float* __restrict__ b1,
    const float* __restrict__ U1T, const float* __restrict__ Ab,
    const float* __restrict__ Df,  const float* __restrict__ D,
    float* __restrict__ out)
{
    const int bid  = blockIdx.x;
    const int tid  = threadIdx.x;
    const int lane = tid & 63;                 // = o2
    const int w    = rfl(tid >> 6);            // uniform

    const int s = bid >> 3, q = bid & 7;
    const int b = q * 4 + w;                   // this wave's b (uniform)

    float acc = D[b * 64 + lane] + b1[lane];   // coalesced 256B load

    #pragma unroll
    for (int hh = 0; hh < 2; ++hh) {           // two 32-wide o-halves
        const int o0 = hh * 32;
        float u[32], wc[32];
        #pragma unroll
        for (int j = 0; j < 32; ++j)
            u[j] = U1T[(o0 + j) * 64 + lane];  // coalesced across lanes
        const float4* wrow = (const float4*)(W1 + (size_t)lane * K1 + s * 64 + o0);
        #pragma unroll
        for (int qq = 0; qq < 8; ++qq) {       // per-lane contiguous 128B
            const float4 v = wrow[qq];
            wc[qq*4] = v.x; wc[qq*4+1] = v.y; wc[qq*4+2] = v.z; wc[qq*4+3] = v.w;
        }
        const float* ap = Ab + ((size_t)(b * S + s)) * 64 + o0;  // uniform -> s_load
        const float* dp = Df + ((size_t)(b * S + s)) * 64 + o0;
        float t0 = 0.f;
        #pragma unroll
        for (int j = 0; j < 32; ++j)
            t0 += ap[j] * u[j] + dp[j] * wc[j];
        acc += t0;
    }

    out[((size_t)(b * S + s)) * 64 + lane] = acc;  // coalesced
}

// ---------------------------------------------------------------------------
extern "C" void kernel_launch(void* const* d_in, const int* in_sizes, int n_in,
                              void* d_out, int out_size, void* d_ws, size_t ws_size,
                              hipStream_t stream)
{
    const float* h  = (const float*)d_in[0];
    const float* W0 = (const float*)d_in[1];
    const float* b0 = (const float*)d_in[2];
    const float* Ws = (const float*)d_in[3];
    const float* bs = (const float*)d_in[4];
    const float* W1 = (const float*)d_in[5];
    const float* b1 = (const float*)d_in[6];
    float* out = (float*)d_out;

    float* ws  = (float*)d_ws;
    float* U1T = ws;                       // 4096
    float* Ab  = U1T + 64 * 64;            // 262144
    float* Df  = Ab  + ROWS * 64;          // 262144
    float* C   = Df  + ROWS * 64;          // 262144
    float* D   = C   + ROWS * 64;          // 2048
    // total: ~3.0 MB of d_ws; every element read is written first each call.

    prep_kernel <<<512,  256, 0, stream>>>(h, W0, b0, Ws, bs, W1, U1T, Ab, Df, C);
    dmid_kernel <<<512,  256, 0, stream>>>(C, W1, D);
    final_kernel<<<1024, 256, 0, stream>>>(W1, b1, U1T, Ab, Df, D, out);
}

// Round 14
// 37.040 us; speedup vs baseline: 2.5724x; 1.0074x over previous
//
#include <hip/hip_runtime.h>

// Sizes fixed by the problem.
#define B   32
#define S   128
#define IN  64
#define ROWS (B*S)      // 4096
#define K1  (S*IN)      // 8192

__device__ __forceinline__ int rfl(int x) { return __builtin_amdgcn_readfirstlane(x); }

// ---------------------------------------------------------------------------
// Kernel 1: "prep" — 512 blocks (2/CU). 8 rows/block, 2 rows/wave. LDS-free.
//   'bsi,oi->bso': o indexes ROWS of W0/Ws -> lane o reads weight row `lane`.
//   h rows wave-uniform -> scalar pipe.
//   Side jobs: U1T[o][o2] (8 outputs/block) and W1T[k][o2] = W1[o2][k]
//   (one 256-k chunk per wave; coalesced read, scattered-once write) so that
//   final's W1-slice reads become coalesced.
// ---------------------------------------------------------------------------
__global__ __launch_bounds__(256, 2) void prep_kernel(
    const float* __restrict__ h,  const float* __restrict__ W0,
    const float* __restrict__ b0, const float* __restrict__ Ws,
    const float* __restrict__ bs, const float* __restrict__ W1,
    float* __restrict__ U1T, float* __restrict__ W1T,
    float* __restrict__ Ab,  float* __restrict__ Df,
    float* __restrict__ C)
{
    const int bid  = blockIdx.x;
    const int tid  = threadIdx.x;
    const int lane = tid & 63;                 // = o
    const int w    = rfl(tid >> 6);            // wave id, uniform

    const int row0 = bid * 8 + w * 2;          // this wave's 2 rows (uniform)
    const float4* w0row = (const float4*)(W0 + (size_t)lane * 128);
    const float4* wsrow = (const float4*)(Ws + (size_t)lane * 64);

    float a[2] = {0,0}, c[2] = {0,0}, sf[2] = {0,0};
    #pragma unroll
    for (int ic = 0; ic < 4; ++ic) {           // i-chunks of 16 (VGPR control)
        const int i0 = ic * 16;
        float wa[16], wb[16], wsv[16];
        #pragma unroll
        for (int q = 0; q < 4; ++q) {          // per-lane contiguous 16B loads
            const float4 va = w0row[ic * 4 + q];
            const float4 vb = w0row[16 + ic * 4 + q];
            const float4 vs = wsrow[ic * 4 + q];
            wa [q*4] = va.x; wa [q*4+1] = va.y; wa [q*4+2] = va.z; wa [q*4+3] = va.w;
            wb [q*4] = vb.x; wb [q*4+1] = vb.y; wb [q*4+2] = vb.z; wb [q*4+3] = vb.w;
            wsv[q*4] = vs.x; wsv[q*4+1] = vs.y; wsv[q*4+2] = vs.z; wsv[q*4+3] = vs.w;
        }
        #pragma unroll
        for (int r = 0; r < 2; ++r) {
            const float* hp = h + (size_t)(row0 + r) * 64 + i0;  // uniform -> s_load
            #pragma unroll
            for (int j = 0; j < 16; ++j) {
                const float hv = hp[j];
                a [r] += hv * wa [j];
                c [r] += hv * wb [j];
                sf[r] += hv * wsv[j];
            }
        }
    }
    const float b0v = b0[lane], bsv = bs[lane];
    #pragma unroll
    for (int r = 0; r < 2; ++r) {
        const int row = row0 + r;
        const float ab = a[r] + b0v;
        Ab[row * 64 + lane] = ab;              // coalesced stores
        C [row * 64 + lane] = c[r];
        Df[row * 64 + lane] = sf[r] + bsv - ab - c[r];
    }

    // U1T[o][o2] = sum_t W1[o2, t*64+o]; 8 outputs/block, 32 lanes each.
    {
        const int g   = bid * 8 + (tid >> 5);  // 0..4095
        const int o2  = g >> 6, o = g & 63;
        const int sub = tid & 31;
        float acc = 0.f;
        #pragma unroll
        for (int u = 0; u < 4; ++u)
            acc += W1[(size_t)o2 * K1 + (sub + 32 * u) * 64 + o];
        #pragma unroll
        for (int m = 16; m; m >>= 1) acc += __shfl_xor(acc, m);  // 32-group
        if (sub == 0) U1T[o * 64 + o2] = acc;
    }

    // W1T[k][o2] = W1[o2][k]; one 256-k chunk per wave (2048 waves total).
    {
        const int g2 = bid * 4 + w;            // 0..2047
        const int r2 = g2 >> 5;                // o2 row (uniform)
        const int ch = g2 & 31;                // k-chunk (uniform)
        const float4 wv = *(const float4*)(W1 + (size_t)r2 * K1 + ch * 256 + lane * 4);
        const size_t kbase = (size_t)(ch * 256 + lane * 4);
        W1T[(kbase + 0) * 64 + r2] = wv.x;
        W1T[(kbase + 1) * 64 + r2] = wv.y;
        W1T[(kbase + 2) * 64 + r2] = wv.z;
        W1T[(kbase + 3) * 64 + r2] = wv.w;
    }
}

// ---------------------------------------------------------------------------
// Kernel 2: "dmid" — D[b][o2] = sum_k C[b,k] * W1[o2,k], computed directly.
//   One wave per (b,o2); g = o2*32 + b so a block's 4 waves SHARE the same
//   W1 row (L1 reuse x4 -> W1 L2 traffic 67->17MB). Fully coalesced loads,
//   6-step shfl reduce. No partials buffer.
// ---------------------------------------------------------------------------
__global__ __launch_bounds__(256, 2) void dmid_kernel(
    const float* __restrict__ C, const float* __restrict__ W1,
    float* __restrict__ D)
{
    const int bid  = blockIdx.x;
    const int tid  = threadIdx.x;
    const int lane = tid & 63;
    const int w    = rfl(tid >> 6);            // uniform

    const int g  = bid * 4 + w;                // 0..2047
    const int o2 = g >> 5, b = g & 31;         // block shares o2 (uniform)

    const float4* wrow = (const float4*)(W1 + (size_t)o2 * K1) + lane;
    const float4* crow = (const float4*)(C  + (size_t)b  * K1) + lane;

    float s0 = 0, s1 = 0, s2 = 0, s3 = 0;
    #pragma unroll
    for (int j = 0; j < 32; ++j) {             // k = j*256 + lane*4 + 0..3
        const float4 w4 = wrow[j * 64];        // coalesced 1KB across lanes
        const float4 c4 = crow[j * 64];        // coalesced 1KB across lanes
        s0 += c4.x * w4.x; s1 += c4.y * w4.y;
        s2 += c4.z * w4.z; s3 += c4.w * w4.w;
    }
    float acc = (s0 + s1) + (s2 + s3);
    #pragma unroll
    for (int m = 32; m; m >>= 1) acc += __shfl_xor(acc, m);
    if (lane == 0) D[b * 64 + o2] = acc;
}

// ---------------------------------------------------------------------------
// Kernel 3: "finalk" — 1024 blocks (4/CU). block = (s 0..127) x (q 0..7),
//   one b = q*4+w per wave.
//   out[b,s,o2] = D[b,o2] + b1[o2]
//               + sum_o Ab[b,s,o]*U1T[o][o2] + Df[b,s,o]*W1T[s*64+o][o2]
//   All LDS-free; U1T/W1T reads coalesced across lanes (o2), Ab/Df scalar.
// ---------------------------------------------------------------------------
__global__ __launch_bounds__(256, 4) void final_kernel(
    const float* __restrict__ b1,  const float* __restrict__ U1T,
    const float* __restrict__ W1T, const float* __restrict__ Ab,
    const float* __restrict__ Df,  const float* __restrict__ D,
    float* __restrict__ out)
{
    const int bid  = blockIdx.x;
    const int tid  = threadIdx.x;
    const int lane = tid & 63;                 // = o2
    const int w    = rfl(tid >> 6);            // uniform

    const int s = bid >> 3, q = bid & 7;
    const int b = q * 4 + w;                   // this wave's b (uniform)

    float acc = D[b * 64 + lane] + b1[lane];   // coalesced 256B load

    #pragma unroll
    for (int hh = 0; hh < 2; ++hh) {           // two 32-wide o-halves
        const int o0 = hh * 32;
        float u[32], wc[32];
        #pragma unroll
        for (int j = 0; j < 32; ++j)
            u[j] = U1T[(o0 + j) * 64 + lane];                  // coalesced
        #pragma unroll
        for (int j = 0; j < 32; ++j)
            wc[j] = W1T[(size_t)(s * 64 + o0 + j) * 64 + lane]; // coalesced
        const float* ap = Ab + ((size_t)(b * S + s)) * 64 + o0;  // uniform -> s_load
        const float* dp = Df + ((size_t)(b * S + s)) * 64 + o0;
        float t0 = 0.f;
        #pragma unroll
        for (int j = 0; j < 32; ++j)
            t0 += ap[j] * u[j] + dp[j] * wc[j];
        acc += t0;
    }

    out[((size_t)(b * S + s)) * 64 + lane] = acc;  // coalesced
}

// ---------------------------------------------------------------------------
extern "C" void kernel_launch(void* const* d_in, const int* in_sizes, int n_in,
                              void* d_out, int out_size, void* d_ws, size_t ws_size,
                              hipStream_t stream)
{
    const float* h  = (const float*)d_in[0];
    const float* W0 = (const float*)d_in[1];
    const float* b0 = (const float*)d_in[2];
    const float* Ws = (const float*)d_in[3];
    const float* bs = (const float*)d_in[4];
    const float* W1 = (const float*)d_in[5];
    const float* b1 = (const float*)d_in[6];
    float* out = (float*)d_out;

    float* ws  = (float*)d_ws;
    float* U1T = ws;                       // 4096
    float* W1T = U1T + 64 * 64;            // 524288 (2 MB)
    float* Ab  = W1T + K1 * 64;            // 262144
    float* Df  = Ab  + ROWS * 64;          // 262144
    float* C   = Df  + ROWS * 64;          // 262144
    float* D   = C   + ROWS * 64;          // 2048
    // total: ~5.1 MB of d_ws; every element read is written first each call.

    prep_kernel <<<512,  256, 0, stream>>>(h, W0, b0, Ws, bs, W1,
                                           U1T, W1T, Ab, Df, C);
    dmid_kernel <<<512,  256, 0, stream>>>(C, W1, D);
    final_kernel<<<1024, 256, 0, stream>>>(b1, U1T, W1T, Ab, Df, D, out);
}

// Round 15
// 36.628 us; speedup vs baseline: 2.6013x; 1.0112x over previous
//
#include <hip/hip_runtime.h>

// Sizes fixed by the problem.
#define B   32
#define S   128
#define IN  64
#define ROWS (B*S)      // 4096
#define K1  (S*IN)      // 8192

__device__ __forceinline__ int rfl(int x) { return __builtin_amdgcn_readfirstlane(x); }

// ---------------------------------------------------------------------------
// Kernel 1: "prep" — 512 blocks (2/CU). 8 rows/block, 2 rows/wave. LDS-free.
//   'bsi,oi->bso': o indexes ROWS of W0/Ws -> lane o reads weight row `lane`.
//   h rows wave-uniform -> scalar pipe. (U1T/W1T moved to dmid: W1 is no
//   longer touched here at all.)
// ---------------------------------------------------------------------------
__global__ __launch_bounds__(256, 2) void prep_kernel(
    const float* __restrict__ h,  const float* __restrict__ W0,
    const float* __restrict__ b0, const float* __restrict__ Ws,
    const float* __restrict__ bs,
    float* __restrict__ Ab, float* __restrict__ Df, float* __restrict__ C)
{
    const int bid  = blockIdx.x;
    const int tid  = threadIdx.x;
    const int lane = tid & 63;                 // = o
    const int w    = rfl(tid >> 6);            // wave id, uniform

    const int row0 = bid * 8 + w * 2;          // this wave's 2 rows (uniform)
    const float4* w0row = (const float4*)(W0 + (size_t)lane * 128);
    const float4* wsrow = (const float4*)(Ws + (size_t)lane * 64);

    float a[2] = {0,0}, c[2] = {0,0}, sf[2] = {0,0};
    #pragma unroll
    for (int ic = 0; ic < 4; ++ic) {           // i-chunks of 16 (VGPR control)
        const int i0 = ic * 16;
        float wa[16], wb[16], wsv[16];
        #pragma unroll
        for (int q = 0; q < 4; ++q) {          // per-lane contiguous 16B loads
            const float4 va = w0row[ic * 4 + q];
            const float4 vb = w0row[16 + ic * 4 + q];
            const float4 vs = wsrow[ic * 4 + q];
            wa [q*4] = va.x; wa [q*4+1] = va.y; wa [q*4+2] = va.z; wa [q*4+3] = va.w;
            wb [q*4] = vb.x; wb [q*4+1] = vb.y; wb [q*4+2] = vb.z; wb [q*4+3] = vb.w;
            wsv[q*4] = vs.x; wsv[q*4+1] = vs.y; wsv[q*4+2] = vs.z; wsv[q*4+3] = vs.w;
        }
        #pragma unroll
        for (int r = 0; r < 2; ++r) {
            const float* hp = h + (size_t)(row0 + r) * 64 + i0;  // uniform -> s_load
            #pragma unroll
            for (int j = 0; j < 16; ++j) {
                const float hv = hp[j];
                a [r] += hv * wa [j];
                c [r] += hv * wb [j];
                sf[r] += hv * wsv[j];
            }
        }
    }
    const float b0v = b0[lane], bsv = bs[lane];
    #pragma unroll
    for (int r = 0; r < 2; ++r) {
        const int row = row0 + r;
        const float ab = a[r] + b0v;
        Ab[row * 64 + lane] = ab;              // coalesced stores
        C [row * 64 + lane] = c[r];
        Df[row * 64 + lane] = sf[r] + bsv - ab - c[r];
    }
}

// ---------------------------------------------------------------------------
// Kernel 2: "dmid" — single pass over W1 produces D, W1T, and U1T.
//   One wave per (o2,b): streams W1 row o2 (32 coalesced float4/lane).
//   - D[b][o2]: dot with C row b (coalesced), 6-step shfl reduce.
//   - W1T chunk b of row o2: the j==b load, re-stored transposed (no reload).
//   - U1T row o2 (b==0 waves only): per-lane column partials u.c (k%64 is
//     j-independent), orbit-reduce via shfl_xor(16,32), lanes<16 store.
//   W1 is read exactly ONCE per call, here.
// ---------------------------------------------------------------------------
__global__ __launch_bounds__(256, 2) void dmid_kernel(
    const float* __restrict__ C, const float* __restrict__ W1,
    float* __restrict__ D, float* __restrict__ U1T, float* __restrict__ W1T)
{
    const int bid  = blockIdx.x;
    const int tid  = threadIdx.x;
    const int lane = tid & 63;
    const int w    = rfl(tid >> 6);            // uniform

    const int g  = bid * 4 + w;                // 0..2047
    const int o2 = g >> 5, b = g & 31;         // uniform; block shares o2 (L1 reuse)

    const float4* wrow = (const float4*)(W1 + (size_t)o2 * K1) + lane;
    const float4* crow = (const float4*)(C  + (size_t)b  * K1) + lane;

    float s0 = 0, s1 = 0, s2 = 0, s3 = 0;      // D partials
    float u0 = 0, u1 = 0, u2 = 0, u3 = 0;      // U1T column partials
    float4 sv = make_float4(0.f, 0.f, 0.f, 0.f);  // saved j==b chunk for W1T

    #pragma unroll
    for (int j = 0; j < 32; ++j) {             // k = j*256 + lane*4 + 0..3
        const float4 w4 = wrow[j * 64];        // coalesced 1KB across lanes
        const float4 c4 = crow[j * 64];        // coalesced 1KB across lanes
        s0 += c4.x * w4.x; s1 += c4.y * w4.y;
        s2 += c4.z * w4.z; s3 += c4.w * w4.w;
        u0 += w4.x; u1 += w4.y; u2 += w4.z; u3 += w4.w;
        if (j == b) sv = w4;                   // wave-uniform select, unrolled j
    }

    // D[b][o2]
    float acc = (s0 + s1) + (s2 + s3);
    #pragma unroll
    for (int m = 32; m; m >>= 1) acc += __shfl_xor(acc, m);
    if (lane == 0) D[b * 64 + o2] = acc;

    // W1T[k][o2] for k in chunk b (zero extra loads)
    {
        const size_t kbase = (size_t)b * 256 + lane * 4;
        W1T[(kbase + 0) * 64 + o2] = sv.x;
        W1T[(kbase + 1) * 64 + o2] = sv.y;
        W1T[(kbase + 2) * 64 + o2] = sv.z;
        W1T[(kbase + 3) * 64 + o2] = sv.w;
    }

    // U1T[o][o2] = sum_t W1[o2, t*64+o]: one wave per o2 (b==0)
    if (b == 0) {
        u0 += __shfl_xor(u0, 16); u0 += __shfl_xor(u0, 32);
        u1 += __shfl_xor(u1, 16); u1 += __shfl_xor(u1, 32);
        u2 += __shfl_xor(u2, 16); u2 += __shfl_xor(u2, 32);
        u3 += __shfl_xor(u3, 16); u3 += __shfl_xor(u3, 32);
        if (lane < 16) {                       // o = 4*lane + c
            U1T[(4 * lane + 0) * 64 + o2] = u0;
            U1T[(4 * lane + 1) * 64 + o2] = u1;
            U1T[(4 * lane + 2) * 64 + o2] = u2;
            U1T[(4 * lane + 3) * 64 + o2] = u3;
        }
    }
}

// ---------------------------------------------------------------------------
// Kernel 3: "finalk" — 1024 blocks (4/CU). block = (s 0..127) x (q 0..7),
//   one b = q*4+w per wave.
//   out[b,s,o2] = D[b,o2] + b1[o2]
//               + sum_o Ab[b,s,o]*U1T[o][o2] + Df[b,s,o]*W1T[s*64+o][o2]
//   All LDS-free; U1T/W1T reads coalesced across lanes (o2), Ab/Df scalar.
// ---------------------------------------------------------------------------
__global__ __launch_bounds__(256, 4) void final_kernel(
    const float* __restrict__ b1,  const float* __restrict__ U1T,
    const float* __restrict__ W1T, const float* __restrict__ Ab,
    const float* __restrict__ Df,  const float* __restrict__ D,
    float* __restrict__ out)
{
    const int bid  = blockIdx.x;
    const int tid  = threadIdx.x;
    const int lane = tid & 63;                 // = o2
    const int w    = rfl(tid >> 6);            // uniform

    const int s = bid >> 3, q = bid & 7;
    const int b = q * 4 + w;                   // this wave's b (uniform)

    float acc = D[b * 64 + lane] + b1[lane];   // coalesced 256B load

    #pragma unroll
    for (int hh = 0; hh < 2; ++hh) {           // two 32-wide o-halves
        const int o0 = hh * 32;
        float u[32], wc[32];
        #pragma unroll
        for (int j = 0; j < 32; ++j)
            u[j] = U1T[(o0 + j) * 64 + lane];                   // coalesced
        #pragma unroll
        for (int j = 0; j < 32; ++j)
            wc[j] = W1T[(size_t)(s * 64 + o0 + j) * 64 + lane]; // coalesced
        const float* ap = Ab + ((size_t)(b * S + s)) * 64 + o0;  // uniform -> s_load
        const float* dp = Df + ((size_t)(b * S + s)) * 64 + o0;
        float t0 = 0.f;
        #pragma unroll
        for (int j = 0; j < 32; ++j)
            t0 += ap[j] * u[j] + dp[j] * wc[j];
        acc += t0;
    }

    out[((size_t)(b * S + s)) * 64 + lane] = acc;  // coalesced
}

// ---------------------------------------------------------------------------
extern "C" void kernel_launch(void* const* d_in, const int* in_sizes, int n_in,
                              void* d_out, int out_size, void* d_ws, size_t ws_size,
                              hipStream_t stream)
{
    const float* h  = (const float*)d_in[0];
    const float* W0 = (const float*)d_in[1];
    const float* b0 = (const float*)d_in[2];
    const float* Ws = (const float*)d_in[3];
    const float* bs = (const float*)d_in[4];
    const float* W1 = (const float*)d_in[5];
    const float* b1 = (const float*)d_in[6];
    float* out = (float*)d_out;

    float* ws  = (float*)d_ws;
    float* U1T = ws;                       // 4096
    float* W1T = U1T + 64 * 64;            // 524288 (2 MB)
    float* Ab  = W1T + K1 * 64;            // 262144
    float* Df  = Ab  + ROWS * 64;          // 262144
    float* C   = Df  + ROWS * 64;          // 262144
    float* D   = C   + ROWS * 64;          // 2048
    // total: ~5.1 MB of d_ws; every element read is written first each call.

    prep_kernel <<<512,  256, 0, stream>>>(h, W0, b0, Ws, bs, Ab, Df, C);
    dmid_kernel <<<512,  256, 0, stream>>>(C, W1, D, U1T, W1T);
    final_kernel<<<1024, 256, 0, stream>>>(b1, U1T, W1T, Ab, Df, D, out);
}